// Round 5
// baseline (1096.697 us; speedup 1.0000x reference)
//
#include <hip/hip_runtime.h>
#include <hip/hip_bf16.h>
#include <hip/hip_fp16.h>

#define F_IN 512
#define NREP 8

// acc layout: per node 32 half2 (128 B = 2 cache lines); j-pair jp (0..7) lives at
// slot(node,jp) = node*32 + (jp&1)*16 + (jp>>1)  -> 4 pairs in line A, 4 in line B.
__device__ __forceinline__ int acc_slot(int node, int jp) {
    return node * 32 + ((jp & 1) << 4) + (jp >> 1);
}

// --- in-degree count, 8 replicated tables to cut same-line atomic serialization ---
__global__ void k_deg(const int* __restrict__ col, int* __restrict__ degr,
                      int nr, int E) {
    int i = blockIdx.x * blockDim.x + threadIdx.x;
    int* tbl = degr + (size_t)(blockIdx.x & (NREP - 1)) * nr;
    if (i < E) atomicAdd(&tbl[col[i]], 1);
}

// --- dinv = rsqrt(sum_replicas + 1) ---
__global__ void k_dinv(const int* __restrict__ degr, float* __restrict__ dinv,
                       int nr, int n) {
    int i = blockIdx.x * blockDim.x + threadIdx.x;
    if (i < n) {
        int d = 1;
        #pragma unroll
        for (int r = 0; r < NREP; ++r) d += degr[(size_t)r * nr + i];
        dinv[i] = rsqrtf((float)d);
    }
}

// --- hs = (x @ W1) * dinv[node] (f16, compact); acc init = hs (padded+swizzled) ---
__global__ __launch_bounds__(256) void k_gemm1(
    const float* __restrict__ x, const float* __restrict__ W1,
    const float* __restrict__ dinv, __half2* __restrict__ hs,
    __half2* __restrict__ acc, int n)
{
    __shared__ float red[4][64 * 17];
    const int lane = threadIdx.x & 63;
    const int wib  = threadIdx.x >> 6;
    const int wave = blockIdx.x * (blockDim.x >> 6) + wib;
    const int nw   = gridDim.x * (blockDim.x >> 6);
    float* rb = red[wib];

    float w[128];
    #pragma unroll
    for (int i = 0; i < 32; ++i) {
        float4 t = ((const float4*)W1)[lane * 32 + i];
        w[4*i+0] = t.x; w[4*i+1] = t.y; w[4*i+2] = t.z; w[4*i+3] = t.w;
    }
    const int q  = lane >> 4;
    const int jj = lane & 15;

    for (int node = wave; node < n; node += nw) {
        const float4* xr = (const float4*)(x + (size_t)node * F_IN);
        float4 a = xr[lane * 2];
        float4 b = xr[lane * 2 + 1];
        float xs[8] = {a.x, a.y, a.z, a.w, b.x, b.y, b.z, b.w};

        float p[16];
        #pragma unroll
        for (int j = 0; j < 16; ++j) p[j] = 0.f;
        #pragma unroll
        for (int i = 0; i < 8; ++i)
            #pragma unroll
            for (int j = 0; j < 16; ++j)
                p[j] = fmaf(xs[i], w[i * 16 + j], p[j]);

        #pragma unroll
        for (int j = 0; j < 16; ++j) rb[lane * 17 + j] = p[j];
        __asm__ volatile("s_waitcnt lgkmcnt(0)" ::: "memory");
        float s = 0.f;
        #pragma unroll
        for (int i = 0; i < 16; ++i) s += rb[(q * 16 + i) * 17 + jj];
        s += __shfl_down(s, 32);
        s += __shfl_down(s, 16);

        float di = dinv[node];
        float sv = s * di;
        float sn = __shfl_down(sv, 1);
        if (lane < 16 && (lane & 1) == 0) {
            int jp = lane >> 1;
            __half2 hv = __halves2half2(__float2half(sv), __float2half(sn));
            hs[node * 8 + jp]       = hv;
            acc[acc_slot(node, jp)] = hv;
        }
    }
}

// --- acc[col[e]] += hs[row[e]], 8 lanes/edge, packed f16 atomics, swizzled dest ---
__global__ void k_scatter(const int* __restrict__ row, const int* __restrict__ col,
                          const __half2* __restrict__ hs, __half2* __restrict__ acc, int E)
{
    int t = blockIdx.x * blockDim.x + threadIdx.x;
    int e = t >> 3;
    if (e < E) {
        int jp = t & 7;
        int r = row[e], c = col[e];
        unsafeAtomicAdd(&acc[acc_slot(c, jp)], hs[r * 8 + jp]);
    }
}

// --- layer-2: v = relu(acc*dinv + b1); hs2 = (v @ W2) * dinv; acc updated in place ---
__global__ void k_gemm2(__half2* __restrict__ acc, __half2* __restrict__ hs2,
                        const float* __restrict__ dinv,
                        const float* __restrict__ b1, const float* __restrict__ W2,
                        int n)
{
    int t = blockIdx.x * blockDim.x + threadIdx.x;
    int node = t >> 4, j = t & 15;
    if (node >= n) return;
    int jp = j >> 1;
    int slot = acc_slot(node, jp);
    __half2 pair = acc[slot];
    float av = (j & 1) ? __half2float(__high2half(pair)) : __half2float(__low2half(pair));
    float di = dinv[node];
    float v = fmaxf(av * di + b1[j], 0.f);
    float h2 = 0.f;
    #pragma unroll
    for (int k = 0; k < 16; ++k) {
        float ok = __shfl(v, k, 16);
        h2 = fmaf(ok, W2[k * 16 + j], h2);
    }
    float o  = h2 * di;
    float o1 = __shfl_down(o, 1);
    if ((j & 1) == 0) {
        __half2 hv = __halves2half2(__float2half(o), __float2half(o1));
        hs2[node * 8 + jp] = hv;
        acc[slot]          = hv;     // same lanes read this slot above -> safe
    }
}

// --- final: v = acc*dinv + b2; log_softmax over 16 classes; fp32 out ---
__global__ void k_final(const __half2* __restrict__ acc, const float* __restrict__ dinv,
                        const float* __restrict__ b2, float* __restrict__ out, int n)
{
    int t = blockIdx.x * blockDim.x + threadIdx.x;
    int node = t >> 4, j = t & 15;
    if (node >= n) return;
    int jp = j >> 1;
    __half2 pair = acc[acc_slot(node, jp)];
    float av = (j & 1) ? __half2float(__high2half(pair)) : __half2float(__low2half(pair));
    float v = av * dinv[node] + b2[j];
    float m = v;
    #pragma unroll
    for (int off = 8; off >= 1; off >>= 1) m = fmaxf(m, __shfl_xor(m, off));
    float e = expf(v - m);
    float s = e;
    #pragma unroll
    for (int off = 8; off >= 1; off >>= 1) s += __shfl_xor(s, off);
    out[node * 16 + j] = v - m - logf(s);
}

extern "C" void kernel_launch(void* const* d_in, const int* in_sizes, int n_in,
                              void* d_out, int out_size, void* d_ws, size_t ws_size,
                              hipStream_t stream)
{
    const float* x  = (const float*)d_in[0];
    const int*   ei = (const int*)d_in[1];   // [2, E]: row then col
    const float* W1 = (const float*)d_in[2];
    const float* b1 = (const float*)d_in[3];
    const float* W2 = (const float*)d_in[4];
    const float* b2 = (const float*)d_in[5];
    float* out = (float*)d_out;

    const int n  = in_sizes[0] / F_IN;       // 100000
    const int E  = in_sizes[1] / 2;          // 3.2M
    const int nr = (n + 63) & ~63;           // replica stride (line-aligned)

    // ws: degr (8*nr int) | dinv (n f32) | hs (n*8 half2) | acc (n*32 half2, padded)
    char* ws = (char*)d_ws;
    size_t szR = (size_t)NREP * nr * 4;
    size_t szN = (((size_t)n * 4) + 511) & ~(size_t)511;
    size_t szH = (((size_t)n * 16 * 2) + 511) & ~(size_t)511;
    int*     degr = (int*)(ws);
    float*   dinv = (float*)(ws + szR);
    __half2* hs   = (__half2*)(ws + szR + szN);
    __half2* acc  = (__half2*)(ws + szR + szN + szH);

    hipMemsetAsync(degr, 0, szR, stream);
    k_deg <<<(E + 255) / 256, 256, 0, stream>>>(ei + E, degr, nr, E);
    k_dinv<<<(n + 255) / 256, 256, 0, stream>>>(degr, dinv, nr, n);

    // layer 1
    k_gemm1  <<<2048, 256, 0, stream>>>(x, W1, dinv, hs, acc, n);
    k_scatter<<<(E * 8 + 255) / 256, 256, 0, stream>>>(ei, ei + E, hs, acc, E);

    // layer 2 (hs2 reuses hs; acc updated in place)
    k_gemm2  <<<(n * 16 + 255) / 256, 256, 0, stream>>>(acc, hs, dinv, b1, W2, n);
    k_scatter<<<(E * 8 + 255) / 256, 256, 0, stream>>>(ei, ei + E, hs, acc, E);

    // epilogue
    k_final  <<<(n * 16 + 255) / 256, 256, 0, stream>>>(acc, dinv, b2, out, n);
}